// Round 4
// baseline (496.424 us; speedup 1.0000x reference)
//
#include <hip/hip_runtime.h>
#include <hip/hip_bf16.h>

// Sinkhorn on MI355X. B=64, L=1024, D=256.
// prep (norms + minmax init) -> gemm (K=exp(cos-1) fp16; epilogue also emits
//   p0 = per-tile-row column-sum partials when strategy A)
//   -> 10x fused F: v=w2/(reduce p + eps); z=Kv; u=w1/(z+eps); p'=partials(K^T u)
//   -> fin (out = minmax-norm(u*K*v^T) * (-log K))
// Strategy A (ws >= 138.9 MB): 16 row-strips/batch, grid 1024, no ktu0 pass.
// Strategy B (ws >= 135.8 MB): round-3 proven config (4 strips, ktu0 pass).

#define EPSV 1e-12f
#define W1 0.0009765625f   // 1/1024

typedef short  short8 __attribute__((ext_vector_type(8)));
typedef float  f32x4  __attribute__((ext_vector_type(4)));
typedef _Float16 h8   __attribute__((ext_vector_type(8)));
typedef _Float16 h2   __attribute__((ext_vector_type(2)));

// load 8 consecutive floats, convert to 8 bf16 (hw v_cvt_pk_bf16_f32)
__device__ __forceinline__ short8 ld_cvt8(const float* p) {
  float4 f0 = *(const float4*)p;
  float4 f1 = *(const float4*)(p + 4);
  float2 p0; p0.x = f0.x; p0.y = f0.y;
  float2 p1; p1.x = f0.z; p1.y = f0.w;
  float2 p2; p2.x = f1.x; p2.y = f1.y;
  float2 p3; p3.x = f1.z; p3.y = f1.w;
  __hip_bfloat162 h0 = __float22bfloat162_rn(p0);
  __hip_bfloat162 h1 = __float22bfloat162_rn(p1);
  __hip_bfloat162 h2_ = __float22bfloat162_rn(p2);
  __hip_bfloat162 h3 = __float22bfloat162_rn(p3);
  short2 a = *(short2*)&h0, b = *(short2*)&h1, c = *(short2*)&h2_, d = *(short2*)&h3;
  short8 r;
  r[0] = a.x; r[1] = a.y; r[2] = b.x; r[3] = b.y;
  r[4] = c.x; r[5] = c.y; r[6] = d.x; r[7] = d.y;
  return r;
}

// ---------------------------------------------------------------- diag
__global__ __launch_bounds__(256) void diag_kernel(float* __restrict__ out,
                                                   float val, int n) {
  int stride = gridDim.x * 256;
  for (int i = blockIdx.x * 256 + threadIdx.x; i < n; i += stride) out[i] = val;
}

// ---------------------------------------------------------------- prep
// rows 0..65535 -> x1 norms, 65536..131071 -> x2 norms. 1 wave/row.
__global__ __launch_bounds__(256) void prep_kernel(
    const float* __restrict__ x1, const float* __restrict__ x2,
    float* __restrict__ n1, float* __restrict__ n2,
    unsigned* __restrict__ mm) {
  int t = threadIdx.x, bid = blockIdx.x;
  if (bid == 0 && t < 128) mm[t] = (t < 64) ? 0u : 0x7f800000u;
  int row = bid * 4 + (t >> 6);
  int lane = t & 63;
  const float* xp; float* np_;
  int r = row;
  if (row < 65536) { xp = x1; np_ = n1; }
  else { r = row - 65536; xp = x2; np_ = n2; }
  float4 v = ((const float4*)(xp + (size_t)r * 256))[lane];
  float s = v.x * v.x + v.y * v.y + v.z * v.z + v.w * v.w;
  #pragma unroll
  for (int off = 1; off < 64; off <<= 1) s += __shfl_xor(s, off, 64);
  if (lane == 0) np_[r] = sqrtf(s);
}

// ---------------------------------------------------------------- gemm
// 128x128 tile, BK=64, 4 waves (2x2 of 64x64), mfma_f32_16x16x32_bf16.
// If p0 != null: epilogue also writes column-sum partials (8 strips of 128
// rows per batch) into p0[b][strip][col] (16-strip-layout base, b<<14).
__global__ __launch_bounds__(256) void gemm_kernel(
    const float* __restrict__ x1, const float* __restrict__ x2,
    const float* __restrict__ n1, const float* __restrict__ n2,
    _Float16* __restrict__ Kh, _Float16* __restrict__ p0) {
  __shared__ __align__(16) unsigned short smem[2 * 128 * 64];  // 32 KB
  __shared__ float csum[4][128];
  unsigned short* As = smem;
  unsigned short* Bs = smem + 128 * 64;
  int bid = blockIdx.x;
  int b = bid >> 6, tile = bid & 63;
  int ti = (tile >> 3) << 7, tj = (tile & 7) << 7;
  int t = threadIdx.x, lane = t & 63, wave = t >> 6;
  int wr = (wave >> 1) << 6, wc = (wave & 1) << 6;
  const float* Ag = x1 + ((size_t)(b * 1024 + ti)) * 256;
  const float* Bg = x2 + ((size_t)(b * 1024 + tj)) * 256;

  f32x4 acc[4][4];
  f32x4 zero = {0.f, 0.f, 0.f, 0.f};
  #pragma unroll
  for (int m = 0; m < 4; ++m)
    #pragma unroll
    for (int n = 0; n < 4; ++n) acc[m][n] = zero;

  short8 ra[4], rb[4];
  #pragma unroll
  for (int c = 0; c < 4; ++c) {
    int ch = t + (c << 8); int row = ch >> 3, kg = ch & 7;
    ra[c] = ld_cvt8(Ag + row * 256 + kg * 8);
    rb[c] = ld_cvt8(Bg + row * 256 + kg * 8);
  }

  for (int k0 = 0; k0 < 4; ++k0) {
    __syncthreads();
    #pragma unroll
    for (int c = 0; c < 4; ++c) {
      int ch = t + (c << 8); int row = ch >> 3, kg = ch & 7;
      int kgs = kg ^ (row & 7);
      *(short8*)(As + row * 64 + kgs * 8) = ra[c];
      *(short8*)(Bs + row * 64 + kgs * 8) = rb[c];
    }
    __syncthreads();
    if (k0 < 3) {
      #pragma unroll
      for (int c = 0; c < 4; ++c) {
        int ch = t + (c << 8); int row = ch >> 3, kg = ch & 7;
        ra[c] = ld_cvt8(Ag + row * 256 + (k0 + 1) * 64 + kg * 8);
        rb[c] = ld_cvt8(Bg + row * 256 + (k0 + 1) * 64 + kg * 8);
      }
    }
    #pragma unroll
    for (int ks = 0; ks < 2; ++ks) {
      short8 af[4], bfr[4];
      #pragma unroll
      for (int m = 0; m < 4; ++m) {
        int row = wr + m * 16 + (lane & 15);
        int c16 = (ks << 2) + (lane >> 4);
        af[m] = *(const short8*)(As + row * 64 + ((c16 ^ (row & 7)) << 3));
      }
      #pragma unroll
      for (int n = 0; n < 4; ++n) {
        int row = wc + n * 16 + (lane & 15);
        int c16 = (ks << 2) + (lane >> 4);
        bfr[n] = *(const short8*)(Bs + row * 64 + ((c16 ^ (row & 7)) << 3));
      }
      #pragma unroll
      for (int m = 0; m < 4; ++m)
        #pragma unroll
        for (int n = 0; n < 4; ++n)
          acc[m][n] = __builtin_amdgcn_mfma_f32_16x16x32_bf16(af[m], bfr[n], acc[m][n], 0, 0, 0);
    }
  }
  __syncthreads();

  // epilogue: cos -> K=exp(cos-1) fp16, repack via LDS for coalesced stores
  _Float16* Ct = (_Float16*)smem;  // 128*128 halves = 32 KB
  float a1v[4][4], b2v[4];
  #pragma unroll
  for (int m = 0; m < 4; ++m)
    #pragma unroll
    for (int q = 0; q < 4; ++q)
      a1v[m][q] = n1[(size_t)b * 1024 + ti + wr + m * 16 + ((lane >> 4) << 2) + q];
  #pragma unroll
  for (int n = 0; n < 4; ++n)
    b2v[n] = n2[(size_t)b * 1024 + tj + wc + n * 16 + (lane & 15)];
  #pragma unroll
  for (int m = 0; m < 4; ++m)
    #pragma unroll
    for (int n = 0; n < 4; ++n)
      #pragma unroll
      for (int q = 0; q < 4; ++q) {
        int rl = wr + m * 16 + ((lane >> 4) << 2) + q;
        int cl = wc + n * 16 + (lane & 15);
        float cosv = acc[m][n][q] / (a1v[m][q] * b2v[n] + EPSV);
        Ct[rl * 128 + cl] = (_Float16)__expf(cosv - 1.0f);
      }
  __syncthreads();
  size_t kbase = ((size_t)b << 20);
  #pragma unroll
  for (int c2i = 0; c2i < 8; ++c2i) {
    int c2 = t + (c2i << 8);
    int row = c2 >> 4, seg = c2 & 15;
    *(float4*)(Kh + kbase + (size_t)(ti + row) * 1024 + tj + seg * 8) = ((const float4*)Ct)[c2];
  }
  if (p0 != nullptr) {
    // column sums of this 128x128 tile
    int cg = lane & 15, rsub = lane >> 4;
    float cs[8];
    #pragma unroll
    for (int k = 0; k < 8; ++k) cs[k] = 0.f;
    #pragma unroll
    for (int i = 0; i < 8; ++i) {
      h8 rowv = *(const h8*)&Ct[(wave * 32 + rsub + i * 4) * 128 + cg * 8];
      #pragma unroll
      for (int k = 0; k < 8; ++k) cs[k] += (float)rowv[k];
    }
    #pragma unroll
    for (int k = 0; k < 8; ++k) {
      cs[k] += __shfl_xor(cs[k], 16, 64);
      cs[k] += __shfl_xor(cs[k], 32, 64);
    }
    if (rsub == 0) {
      #pragma unroll
      for (int k = 0; k < 8; ++k) csum[wave][cg * 8 + k] = cs[k];
    }
    __syncthreads();
    if (t < 128) {
      float s = csum[0][t] + csum[1][t] + csum[2][t] + csum[3][t];
      p0[((size_t)b << 14) + ((size_t)(ti >> 7) << 10) + tj + t] = (_Float16)s;
    }
  }
}

// ---------------------------------------------------------------- ktu0 (strategy B only)
// p0 = column sums of K per 256-row strip (u0 = 1). block=(b, strip s of 256).
__global__ __launch_bounds__(512) void ktu0_kernel(
    const _Float16* __restrict__ Kh, _Float16* __restrict__ dst) {
  int bid = blockIdx.x;
  int b = bid >> 2, s = bid & 3;
  int t = threadIdx.x, lane = t & 63, w = t >> 6;
  __shared__ float plds[8][1024];  // 32 KB
  float pacc[16];
  #pragma unroll
  for (int k = 0; k < 16; ++k) pacc[k] = 0.f;
  const _Float16* kp = Kh + ((size_t)b << 20) + (size_t)(s * 256 + w) * 1024 + lane * 8;
  #pragma unroll 2
  for (int it = 0; it < 32; ++it) {
    h8 k0 = *(const h8*)(kp + (size_t)it * 8192);
    h8 k1 = *(const h8*)(kp + (size_t)it * 8192 + 512);
    #pragma unroll
    for (int k = 0; k < 8; ++k) { pacc[k] += (float)k0[k]; pacc[8 + k] += (float)k1[k]; }
  }
  float4 v0 = {pacc[0], pacc[1], pacc[2], pacc[3]};
  float4 v1 = {pacc[4], pacc[5], pacc[6], pacc[7]};
  float4 v2 = {pacc[8], pacc[9], pacc[10], pacc[11]};
  float4 v3 = {pacc[12], pacc[13], pacc[14], pacc[15]};
  *(float4*)&plds[w][lane * 8] = v0;
  *(float4*)&plds[w][lane * 8 + 4] = v1;
  *(float4*)&plds[w][512 + lane * 8] = v2;
  *(float4*)&plds[w][512 + lane * 8 + 4] = v3;
  __syncthreads();
  #pragma unroll
  for (int p = 0; p < 2; ++p) {
    int col = (p << 9) + t;
    float sum = plds[0][col] + plds[1][col] + plds[2][col] + plds[3][col]
              + plds[4][col] + plds[5][col] + plds[6][col] + plds[7][col];
    dst[((size_t)b << 12) + (s << 10) + col] = (_Float16)sum;
  }
}

// ---------------------------------------------------------------- fused F
// BSHIFT: log2(partial-buffer stride per batch) = 10 + log2(strips).
// NSRC: #strips in src to reduce. FINAL: write z + G min/max, no dst.
template<int BSHIFT, int NSRC, int FINAL>
__global__ __launch_bounds__(512, 4) void fused_kernel(
    const _Float16* __restrict__ Kh, const _Float16* __restrict__ src,
    _Float16* __restrict__ dst, float* __restrict__ zb,
    unsigned* __restrict__ mm) {
  constexpr int LOGS = BSHIFT - 10;        // strips this kernel computes
  constexpr int ROWS = 1024 >> LOGS;       // rows per strip
  constexpr int ITERS = ROWS / 8;          // row-iters per wave (8 waves)
  int bid = blockIdx.x;
  int b = bid >> LOGS, s = bid & ((1 << LOGS) - 1);
  int t = threadIdx.x, lane = t & 63, w = t >> 6;
  __shared__ float sv[1024];
  __shared__ float plds[8][1024];  // 32 KB
  __shared__ float red[16];
  {
    int col2 = t << 1;
    const _Float16* sp = src + ((size_t)b << BSHIFT) + col2;
    float y0 = 0.f, y1 = 0.f;
    #pragma unroll
    for (int j = 0; j < NSRC; ++j) {
      h2 vv = *(const h2*)(sp + (j << 10));
      y0 += (float)vv[0]; y1 += (float)vv[1];
    }
    sv[col2] = W1 / (y0 + EPSV);
    sv[col2 + 1] = W1 / (y1 + EPSV);
  }
  __syncthreads();
  float svr[16];
  {
    float4 s0 = *(const float4*)&sv[lane * 8];
    float4 s1 = *(const float4*)&sv[lane * 8 + 4];
    float4 s2 = *(const float4*)&sv[512 + lane * 8];
    float4 s3 = *(const float4*)&sv[512 + lane * 8 + 4];
    svr[0] = s0.x;  svr[1] = s0.y;  svr[2]  = s0.z;  svr[3]  = s0.w;
    svr[4] = s1.x;  svr[5] = s1.y;  svr[6]  = s1.z;  svr[7]  = s1.w;
    svr[8] = s2.x;  svr[9] = s2.y;  svr[10] = s2.z;  svr[11] = s2.w;
    svr[12] = s3.x; svr[13] = s3.y; svr[14] = s3.z;  svr[15] = s3.w;
  }
  float pacc[16];
  #pragma unroll
  for (int k = 0; k < 16; ++k) pacc[k] = 0.f;
  float gmn = 3.4e38f, gmx = 0.f;
  const _Float16* kp = Kh + ((size_t)b << 20) + (size_t)(s * ROWS + w) * 1024 + lane * 8;
  #pragma unroll 2
  for (int it = 0; it < ITERS; ++it) {
    int r = s * ROWS + w + it * 8;
    h8 k0 = *(const h8*)(kp + (size_t)it * 8192);
    h8 k1 = *(const h8*)(kp + (size_t)it * 8192 + 512);
    float dot = 0.f;
    #pragma unroll
    for (int k = 0; k < 8; ++k)
      dot += (float)k0[k] * svr[k] + (float)k1[k] * svr[8 + k];
    #pragma unroll
    for (int off = 1; off < 64; off <<= 1) dot += __shfl_xor(dot, off, 64);
    float u = W1 / (dot + EPSV);
    if (FINAL) {
      if (lane == 0) zb[(b << 10) + r] = dot;
      #pragma unroll
      for (int k = 0; k < 8; ++k) {
        float g0 = u * (float)k0[k] * svr[k];
        float g1 = u * (float)k1[k] * svr[8 + k];
        gmn = fminf(gmn, fminf(g0, g1)); gmx = fmaxf(gmx, fmaxf(g0, g1));
      }
    } else {
      #pragma unroll
      for (int k = 0; k < 8; ++k) {
        pacc[k] += (float)k0[k] * u;
        pacc[8 + k] += (float)k1[k] * u;
      }
    }
  }
  if (!FINAL) {
    float4 v0 = {pacc[0], pacc[1], pacc[2], pacc[3]};
    float4 v1 = {pacc[4], pacc[5], pacc[6], pacc[7]};
    float4 v2 = {pacc[8], pacc[9], pacc[10], pacc[11]};
    float4 v3 = {pacc[12], pacc[13], pacc[14], pacc[15]};
    *(float4*)&plds[w][lane * 8] = v0;
    *(float4*)&plds[w][lane * 8 + 4] = v1;
    *(float4*)&plds[w][512 + lane * 8] = v2;
    *(float4*)&plds[w][512 + lane * 8 + 4] = v3;
    __syncthreads();
    #pragma unroll
    for (int p = 0; p < 2; ++p) {
      int col = (p << 9) + t;
      float sum = plds[0][col] + plds[1][col] + plds[2][col] + plds[3][col]
                + plds[4][col] + plds[5][col] + plds[6][col] + plds[7][col];
      dst[((size_t)b << BSHIFT) + (s << 10) + col] = (_Float16)sum;
    }
  } else {
    #pragma unroll
    for (int off = 1; off < 64; off <<= 1) {
      gmn = fminf(gmn, __shfl_xor(gmn, off, 64));
      gmx = fmaxf(gmx, __shfl_xor(gmx, off, 64));
    }
    if (lane == 0) { red[w] = gmn; red[8 + w] = gmx; }
    __syncthreads();
    if (t == 0) {
      float m0 = red[0], m1 = red[8];
      #pragma unroll
      for (int i = 1; i < 8; ++i) { m0 = fminf(m0, red[i]); m1 = fmaxf(m1, red[8 + i]); }
      atomicMin(&mm[64 + b], __float_as_uint(m0));  // positive floats: uint order ok
      atomicMax(&mm[b],      __float_as_uint(m1));
    }
  }
}

// ---------------------------------------------------------------- fin
// out = ((G - gmin) / (gmax - gmin + eps)) * (-log K); v from src partials.
template<int BSHIFT, int NSRC>
__global__ __launch_bounds__(256) void fin_kernel(
    const _Float16* __restrict__ Kh, const _Float16* __restrict__ src,
    const float* __restrict__ zb, const unsigned* __restrict__ mm,
    float* __restrict__ out) {
  int bid = blockIdx.x;
  int b = bid >> 4, rg = bid & 15;
  int t = threadIdx.x, lane = t & 63, w = t >> 6;
  __shared__ float sv[1024];
  #pragma unroll
  for (int p = 0; p < 2; ++p) {
    int col2 = (p << 9) + (t << 1);
    const _Float16* sp = src + ((size_t)b << BSHIFT) + col2;
    float y0 = 0.f, y1 = 0.f;
    #pragma unroll
    for (int j = 0; j < NSRC; ++j) {
      h2 vv = *(const h2*)(sp + (j << 10));
      y0 += (float)vv[0]; y1 += (float)vv[1];
    }
    sv[col2] = W1 / (y0 + EPSV);
    sv[col2 + 1] = W1 / (y1 + EPSV);
  }
  __syncthreads();
  float svr[16];
  {
    float4 s0 = *(const float4*)&sv[lane * 8];
    float4 s1 = *(const float4*)&sv[lane * 8 + 4];
    float4 s2 = *(const float4*)&sv[512 + lane * 8];
    float4 s3 = *(const float4*)&sv[512 + lane * 8 + 4];
    svr[0] = s0.x;  svr[1] = s0.y;  svr[2]  = s0.z;  svr[3]  = s0.w;
    svr[4] = s1.x;  svr[5] = s1.y;  svr[6]  = s1.z;  svr[7]  = s1.w;
    svr[8] = s2.x;  svr[9] = s2.y;  svr[10] = s2.z;  svr[11] = s2.w;
    svr[12] = s3.x; svr[13] = s3.y; svr[14] = s3.z;  svr[15] = s3.w;
  }
  float gmx = __uint_as_float(mm[b]);
  float gmn = __uint_as_float(mm[64 + b]);
  float scale = 1.0f / (gmx - gmn + EPSV);
  const _Float16* kp = Kh + ((size_t)b << 20) + (size_t)(rg * 64 + w) * 1024 + lane * 8;
  float* op = out + ((size_t)b << 20) + (size_t)(rg * 64 + w) * 1024 + lane * 8;
  for (int it = 0; it < 16; ++it) {
    int r = rg * 64 + w + it * 4;
    float u = W1 / (zb[b * 1024 + r] + EPSV);
    h8 k0 = *(const h8*)(kp + (size_t)it * 4096);
    h8 k1 = *(const h8*)(kp + (size_t)it * 4096 + 512);
    float o[16];
    #pragma unroll
    for (int k = 0; k < 8; ++k) {
      float kfa = (float)k0[k];
      float kfb = (float)k1[k];
      float ga = u * kfa * svr[k];
      float gb = u * kfb * svr[8 + k];
      o[k]     = (ga - gmn) * scale * (-__logf(kfa));
      o[8 + k] = (gb - gmn) * scale * (-__logf(kfb));
    }
    float4 o0 = {o[0], o[1], o[2], o[3]};
    float4 o1 = {o[4], o[5], o[6], o[7]};
    float4 o2 = {o[8], o[9], o[10], o[11]};
    float4 o3 = {o[12], o[13], o[14], o[15]};
    *(float4*)(op + (size_t)it * 4096) = o0;
    *(float4*)(op + (size_t)it * 4096 + 4) = o1;
    *(float4*)(op + (size_t)it * 4096 + 512) = o2;
    *(float4*)(op + (size_t)it * 4096 + 516) = o3;
  }
}

// ---------------------------------------------------------------- launch
extern "C" void kernel_launch(void* const* d_in, const int* in_sizes, int n_in,
                              void* d_out, int out_size, void* d_ws, size_t ws_size,
                              hipStream_t stream) {
  const float* x1 = (const float*)d_in[0];
  const float* x2 = (const float*)d_in[1];
  float* out = (float*)d_out;
  char* ws = (char*)d_ws;

  // common layout head
  _Float16* Kh = (_Float16*)(ws);                 // 134217728
  float*    n1 = (float*)(ws + 134217728ULL);     // 262144 (reused as zb)
  float*    zb = (float*)(ws + 134217728ULL);
  float*    n2 = (float*)(ws + 134479872ULL);     // 262144

  // Strategy A: 16-strip partial buffers (2 MB each)
  _Float16* pA16 = (_Float16*)(ws + 134742016ULL);   // 2097152
  _Float16* pB16 = (_Float16*)(ws + 136839168ULL);   // 2097152
  unsigned* mmA  = (unsigned*)(ws + 138936320ULL);   // 512
  const size_t WS_A = 138936832ULL;

  // Strategy B: 4-strip partial buffers (512 KB each) — round-3 proven
  _Float16* pA4 = (_Float16*)(ws + 134742016ULL);    // 524288
  _Float16* pB4 = (_Float16*)(ws + 135266304ULL);    // 524288
  unsigned* mmB = (unsigned*)(ws + 135790592ULL);    // 512
  const size_t WS_B = 135791104ULL;

  if (ws_size >= WS_A) {
    prep_kernel<<<32768, 256, 0, stream>>>(x1, x2, n1, n2, mmA);
    gemm_kernel<<<4096, 256, 0, stream>>>(x1, x2, n1, n2, Kh, pA16);
    // k=1: src = p0 (8 strips in pA16), dst = pB16
    fused_kernel<14, 8, 0><<<1024, 512, 0, stream>>>(Kh, pA16, pB16, zb, mmA);
    for (int k = 2; k <= 9; ++k) {
      _Float16* src = (k & 1) ? pA16 : pB16;
      _Float16* dst = (k & 1) ? pB16 : pA16;
      fused_kernel<14, 16, 0><<<1024, 512, 0, stream>>>(Kh, src, dst, zb, mmA);
    }
    // k=10: src = p9 in pB16; FINAL writes zb + minmax only
    fused_kernel<14, 16, 1><<<1024, 512, 0, stream>>>(Kh, pB16, pA16, zb, mmA);
    fin_kernel<14, 16><<<1024, 256, 0, stream>>>(Kh, pB16, zb, mmA, out);
  } else if (ws_size >= WS_B) {
    prep_kernel<<<32768, 256, 0, stream>>>(x1, x2, n1, n2, mmB);
    gemm_kernel<<<4096, 256, 0, stream>>>(x1, x2, n1, n2, Kh, nullptr);
    ktu0_kernel<<<256, 512, 0, stream>>>(Kh, pA4);
    for (int k = 1; k <= 9; ++k) {
      _Float16* src = (k & 1) ? pA4 : pB4;
      _Float16* dst = (k & 1) ? pB4 : pA4;
      fused_kernel<12, 4, 0><<<256, 512, 0, stream>>>(Kh, src, dst, zb, mmB);
    }
    fused_kernel<12, 4, 1><<<256, 512, 0, stream>>>(Kh, pB4, pA4, zb, mmB);
    fin_kernel<12, 4><<<1024, 256, 0, stream>>>(Kh, pB4, zb, mmB, out);
  } else {
    float val = 100.0f + (float)(ws_size >> 20);
    diag_kernel<<<2048, 256, 0, stream>>>(out, val, out_size);
  }
}